// Round 1
// baseline (232.395 us; speedup 1.0000x reference)
//
#include <hip/hip_runtime.h>
#include <cstdint>
#include <cstddef>

// Problem constants (from reference): v is (B=16, L=16384, D=128) fp32.
// out[b, 2j+e, d] = (e==0 ? min : max)(v[b, p, d], v[b, p+1, d]),
//   p = (2j - s_d) mod L,  s_d = (d==0 ? 0 : 2*(d-1))  (always even).
#define L_DIM 16384
#define D_DIM 128
#define B_DIM 16

#define TR 256          // output rows per block
#define DG 32           // columns per block
#define HALO 64         // shift span within a 32-col group (62) rounded to 64
#define ROWS (TR + HALO) // 320 input rows staged

__global__ __launch_bounds__(256) void butterfly_cmpex_kernel(
    const float* __restrict__ v, float* __restrict__ out) {
  __shared__ float lds[ROWS * DG];  // 40 KB, linear [row][32] layout

  const int rtile = blockIdx.x;  // 0..63
  const int g     = blockIdx.y;  // 0..3  (column group)
  const int b     = blockIdx.z;  // 0..15
  const int r0    = rtile * TR;
  const int d0    = g * DG;
  const int smax  = 64 * g + 60;      // max shift in this column group
  const int rin0  = r0 - smax;        // first staged input row (may be <0)

  const int t    = threadIdx.x;
  const int lane = t & 63;
  const int wave = t >> 6;

  const float* vb = v + (size_t)b * L_DIM * D_DIM;

  // ---- Load: ROWS x 32 floats -> LDS via global_load_lds (16B/lane) ----
  // One chunk = 8 rows x 128B = 1KB = one wave-instr. lane l covers
  // row chunk*8 + l/8, float4-col l%8. LDS dest is linear: base + lane*16.
  const int lrow  = lane >> 3;
  const int lcol4 = lane & 7;
  for (int chunk = wave; chunk < ROWS / 8; chunk += 4) {
    const int grow = (rin0 + chunk * 8 + lrow) & (L_DIM - 1);
    const float* gp = vb + (size_t)grow * D_DIM + d0 + lcol4 * 4;
    float* lp = &lds[chunk * 8 * DG];  // wave-uniform LDS base
    __builtin_amdgcn_global_load_lds(
        (const __attribute__((address_space(1))) uint32_t*)gp,
        (__attribute__((address_space(3))) uint32_t*)lp,
        16 /*bytes per lane*/, 0 /*offset*/, 0 /*aux*/);
  }
  __syncthreads();  // drains vmcnt for global_load_lds

  // ---- Compute: gather diagonal pairs from LDS, min/max, coalesced store ----
  const int c  = t & 31;   // column within group; bank == c -> conflict-free
  const int jg = t >> 5;   // 0..7 pair-row subgroup
  const int d  = d0 + c;
  const int s  = (d == 0) ? 0 : (2 * d - 2);
  const int roff = smax - s;  // lds_row = 2*j_local + roff  (0..TR+61 < ROWS)

  float* outb = out + (size_t)b * L_DIM * D_DIM;

#pragma unroll
  for (int k = 0; k < TR / 16; ++k) {  // 16 iterations
    const int j_local = k * 8 + jg;
    const int lr = 2 * j_local + roff;
    const float a0 = lds[lr * DG + c];
    const float a1 = lds[(lr + 1) * DG + c];
    const float lo = fminf(a0, a1);
    const float hi = fmaxf(a0, a1);
    const size_t o = (size_t)(r0 + 2 * j_local) * D_DIM + d;
    outb[o]         = lo;  // lanes 0..31 cover one 128B segment
    outb[o + D_DIM] = hi;
  }
}

extern "C" void kernel_launch(void* const* d_in, const int* in_sizes, int n_in,
                              void* d_out, int out_size, void* d_ws, size_t ws_size,
                              hipStream_t stream) {
  const float* v = (const float*)d_in[0];
  float* out = (float*)d_out;
  dim3 grid(L_DIM / TR, D_DIM / DG, B_DIM);  // (64, 4, 16)
  dim3 block(256);
  butterfly_cmpex_kernel<<<grid, block, 0, stream>>>(v, out);
}